// Round 1
// 613.385 us; speedup vs baseline: 1.3870x; 1.3870x over previous
//
#include <hip/hip_runtime.h>

#define NB 2048      // query positions
#define NOBS 2048    // observed positions
#define NP 15        // poly features
#define NG 21        // graph features
#define NE 64        // graph dict columns
#define ND 256       // opd dim
#define NK 36        // NP + NG
#define NDD (ND*ND)  // 65536
#define RB 16        // rows (b) per block in expansion
#define CT 4         // columns (j) per thread in expansion

typedef float vfloat4 __attribute__((ext_vector_type(4)));

// ---------------------------------------------------------------------------
// Kernel 1: per-query 1-NN over obs_pos + build 36-entry coefficient vector.
// grid = NB blocks x 256 threads. obs_pos staged in LDS (16 KB).
// Output is TRANSPOSED: coeffT[k][b], so kernel 2 can load per-k row
// coefficients as contiguous float4s (-> s_load_dwordx4).
// ---------------------------------------------------------------------------
__global__ __launch_bounds__(256) void knn_coeff_kernel(
    const float* __restrict__ positions,   // [NB][2]
    const float* __restrict__ obs_pos,     // [NOBS][2]
    const float* __restrict__ poly_dic,    // [NOBS][NP]
    const float* __restrict__ graph_dic,   // [NOBS][NE]
    const float* __restrict__ alpha_poly,  // [NP][NP]
    const float* __restrict__ alpha_graph, // [NE][NG]
    float* __restrict__ coeffT)            // [NK][NB]  (transposed!)
{
    __shared__ float2 sobs[NOBS];
    __shared__ float  sd[256];
    __shared__ int    si[256];
    __shared__ int    sidx;

    const int tid = threadIdx.x;
    const int b   = blockIdx.x;

    const float2* obs2 = (const float2*)obs_pos;
    for (int i = tid; i < NOBS; i += 256) sobs[i] = obs2[i];

    const float qx = positions[2*b + 0];   // wave-uniform -> s_load
    const float qy = positions[2*b + 1];
    __syncthreads();

    // Each thread scans indices tid, tid+256, ... (ascending) -> strict '<'
    // keeps the earliest index within a thread, matching argmin-first.
    float bestd = 3.4e38f;
    int   besti = 0;
    #pragma unroll
    for (int it = 0; it < NOBS/256; ++it) {
        const int i = tid + it*256;
        const float dx = qx - sobs[i].x;
        const float dy = qy - sobs[i].y;
        const float d2 = dx*dx + dy*dy;
        if (d2 < bestd) { bestd = d2; besti = i; }
    }
    sd[tid] = bestd; si[tid] = besti;
    __syncthreads();

    // Tree reduction; on equal d2 prefer the smaller index (argmin-first).
    for (int s = 128; s > 0; s >>= 1) {
        if (tid < s) {
            const float d2 = sd[tid + s];
            const int   i2 = si[tid + s];
            if (d2 < sd[tid] || (d2 == sd[tid] && i2 < si[tid])) {
                sd[tid] = d2; si[tid] = i2;
            }
        }
        __syncthreads();
    }
    if (tid == 0) sidx = si[0];
    __syncthreads();
    const int idx = sidx;

    // coeffT[0:15][b]  = poly_dic[idx] @ alpha_poly
    // coeffT[15:36][b] = graph_dic[idx] @ alpha_graph
    if (tid < NP) {
        float acc = 0.f;
        #pragma unroll
        for (int q = 0; q < NP; ++q)
            acc += poly_dic[idx*NP + q] * alpha_poly[q*NP + tid];
        coeffT[(size_t)tid*NB + b] = acc;
    } else if (tid < NK) {
        const int g = tid - NP;
        float acc = 0.f;
        #pragma unroll
        for (int e = 0; e < NE; ++e)
            acc += graph_dic[idx*NE + e] * alpha_graph[e*NG + g];
        coeffT[(size_t)tid*NB + b] = acc;
    }
}

// ---------------------------------------------------------------------------
// Kernel 2: out[b][j] = sum_k coeffT[k][b] * S_all[k][j]
// k-outer register tiling: each thread owns a 16-row x 4-col accumulator
// tile (64 VGPRs). Per k: one coalesced float4 S load + 16 wave-uniform
// coeff scalars (4 x s_load_dwordx4) feed 64 FMAs -> 16x fewer uniform
// loads per FMA than the previous column-stationary version.
// grid = (NDD/(256*CT), NB/RB) x 256 threads.
// Nontemporal stores keep the 512 MB output stream from evicting the
// S working set out of per-XCD L2 (gridDim.x = 64 = 0 mod 8, so blocks
// sharing columns land on the same XCD).
// ---------------------------------------------------------------------------
__global__ __launch_bounds__(256) void expand_kernel(
    const float* __restrict__ coeffT,   // [NK][NB]
    const float* __restrict__ S_poly,   // [NP][NDD]
    const float* __restrict__ S_graph,  // [NG][NDD]
    float* __restrict__ out)            // [NB][NDD]
{
    const int j  = (blockIdx.x * 256 + threadIdx.x) * CT;
    const int b0 = blockIdx.y * RB;

    float acc[RB][CT];
    #pragma unroll
    for (int r = 0; r < RB; ++r)
        #pragma unroll
        for (int c = 0; c < CT; ++c)
            acc[r][c] = 0.f;

    #pragma unroll 2
    for (int k = 0; k < NP; ++k) {
        const vfloat4 sv = *(const vfloat4*)(S_poly + (size_t)k*NDD + j);
        const float*  cr = coeffT + (size_t)k*NB + b0;     // wave-uniform
        float cv[RB];
        *(vfloat4*)&cv[0]  = *(const vfloat4*)(cr + 0);
        *(vfloat4*)&cv[4]  = *(const vfloat4*)(cr + 4);
        *(vfloat4*)&cv[8]  = *(const vfloat4*)(cr + 8);
        *(vfloat4*)&cv[12] = *(const vfloat4*)(cr + 12);
        #pragma unroll
        for (int r = 0; r < RB; ++r)
            #pragma unroll
            for (int c = 0; c < CT; ++c)
                acc[r][c] += cv[r] * sv[c];
    }

    #pragma unroll 2
    for (int k = 0; k < NG; ++k) {
        const vfloat4 sv = *(const vfloat4*)(S_graph + (size_t)k*NDD + j);
        const float*  cr = coeffT + (size_t)(NP + k)*NB + b0;  // wave-uniform
        float cv[RB];
        *(vfloat4*)&cv[0]  = *(const vfloat4*)(cr + 0);
        *(vfloat4*)&cv[4]  = *(const vfloat4*)(cr + 4);
        *(vfloat4*)&cv[8]  = *(const vfloat4*)(cr + 8);
        *(vfloat4*)&cv[12] = *(const vfloat4*)(cr + 12);
        #pragma unroll
        for (int r = 0; r < RB; ++r)
            #pragma unroll
            for (int c = 0; c < CT; ++c)
                acc[r][c] += cv[r] * sv[c];
    }

    #pragma unroll
    for (int r = 0; r < RB; ++r) {
        vfloat4 v;
        v.x = acc[r][0]; v.y = acc[r][1]; v.z = acc[r][2]; v.w = acc[r][3];
        __builtin_nontemporal_store(
            v, (vfloat4*)(out + (size_t)(b0 + r)*NDD + j));
    }
}

extern "C" void kernel_launch(void* const* d_in, const int* in_sizes, int n_in,
                              void* d_out, int out_size, void* d_ws, size_t ws_size,
                              hipStream_t stream) {
    const float* positions   = (const float*)d_in[0];
    const float* obs_pos     = (const float*)d_in[1];
    const float* poly_dic    = (const float*)d_in[2];
    const float* graph_dic   = (const float*)d_in[3];
    const float* alpha_poly  = (const float*)d_in[4];
    const float* alpha_graph = (const float*)d_in[5];
    const float* S_poly      = (const float*)d_in[6];
    const float* S_graph     = (const float*)d_in[7];
    float* out = (float*)d_out;

    float* coeffT = (float*)d_ws;   // NK*NB floats = 288 KB (transposed)

    knn_coeff_kernel<<<NB, 256, 0, stream>>>(
        positions, obs_pos, poly_dic, graph_dic, alpha_poly, alpha_graph, coeffT);

    dim3 grid2(NDD/(256*CT), NB/RB);
    expand_kernel<<<grid2, 256, 0, stream>>>(coeffT, S_poly, S_graph, out);
}

// Round 2
// 575.261 us; speedup vs baseline: 1.4789x; 1.0663x over previous
//
#include <hip/hip_runtime.h>

#define NB 2048      // query positions
#define NOBS 2048    // observed positions
#define NP 15        // poly features
#define NG 21        // graph features
#define NE 64        // graph dict columns
#define ND 256       // opd dim
#define NK 36        // NP + NG
#define NDD (ND*ND)  // 65536
#define RB 16        // rows (b) per block in expansion
#define CT 4         // columns (j) per thread in expansion
#define QB 8         // queries per block in knn

typedef float vfloat4 __attribute__((ext_vector_type(4)));

// ---------------------------------------------------------------------------
// Kernel 1: batched 1-NN + coefficient build.
// grid = NB/QB = 256 blocks x 256 threads. Each block stages all obs_pos
// (16 KB) + both alpha matrices ONCE and serves QB=8 queries: one query per
// 32-lane half-wave. Reduction is 5 __shfl_xor steps on a packed
// (d2_bits<<32 | idx) key -> min == (min d2, then min idx) == argmin-first.
// Output TRANSPOSED: coeffT[k][b] so kernel 2 loads per-k coeff rows as
// contiguous uniform float4s (s_load_dwordx4).
// ---------------------------------------------------------------------------
__global__ __launch_bounds__(256) void knn_coeff_kernel(
    const float* __restrict__ positions,   // [NB][2]
    const float* __restrict__ obs_pos,     // [NOBS][2]
    const float* __restrict__ poly_dic,    // [NOBS][NP]
    const float* __restrict__ graph_dic,   // [NOBS][NE]
    const float* __restrict__ alpha_poly,  // [NP][NP]
    const float* __restrict__ alpha_graph, // [NE][NG]
    float* __restrict__ coeffT)            // [NK][NB]  (transposed!)
{
    __shared__ float2 sobs[NOBS];      // 16 KB
    __shared__ float  sap[NP*NP];      // 0.9 KB
    __shared__ float  sag[NE*NG];      // 5.25 KB
    __shared__ int    sbest[QB];

    const int tid = threadIdx.x;

    const float2* obs2 = (const float2*)obs_pos;
    for (int i = tid; i < NOBS; i += 256) sobs[i] = obs2[i];
    for (int i = tid; i < NP*NP; i += 256) sap[i] = alpha_poly[i];
    for (int i = tid; i < NE*NG; i += 256) sag[i] = alpha_graph[i];
    __syncthreads();

    const int w    = tid >> 6;      // wave 0..3
    const int lane = tid & 63;
    const int half = lane >> 5;     // 0/1: which query of this wave
    const int l32  = lane & 31;
    const int q    = blockIdx.x * QB + 2*w + half;

    const float qx = positions[2*q + 0];
    const float qy = positions[2*q + 1];

    // Scan: 64 obs per thread. Lanes 0-31 and 32-63 read identical LDS
    // addresses -> broadcast, conflict-free.
    unsigned long long best = ~0ull;
    #pragma unroll 8
    for (int it = 0; it < NOBS/32; ++it) {
        const int i = l32 + it*32;
        const float dx = qx - sobs[i].x;
        const float dy = qy - sobs[i].y;
        const float d2 = dx*dx + dy*dy;
        const unsigned long long key =
            ((unsigned long long)__float_as_uint(d2) << 32) | (unsigned)i;
        if (key < best) best = key;
    }
    // width-32 min-reduce
    #pragma unroll
    for (int m = 16; m > 0; m >>= 1) {
        const unsigned long long o = __shfl_xor(best, m, 32);
        if (o < best) best = o;
    }
    if (l32 == 0) sbest[2*w + half] = (int)(best & 0xffffffffu);
    __syncthreads();

    // QB*NK = 288 coefficient outputs.
    for (int t = tid; t < QB*NK; t += 256) {
        const int qq  = t / NK;
        const int k   = t - qq*NK;
        const int idx = sbest[qq];
        const int b   = blockIdx.x * QB + qq;
        float acc = 0.f;
        if (k < NP) {
            #pragma unroll
            for (int p = 0; p < NP; ++p)
                acc += poly_dic[idx*NP + p] * sap[p*NP + k];
        } else {
            const int g = k - NP;
            #pragma unroll
            for (int e = 0; e < NE; ++e)
                acc += graph_dic[idx*NE + e] * sag[e*NG + g];
        }
        coeffT[(size_t)k*NB + b] = acc;
    }
}

// ---------------------------------------------------------------------------
// Kernel 2: out[b][j] = sum_k coeffT[k][b] * S_all[k][j]
// k-outer register tiling, FULLY UNROLLED k (36 straight-line steps) so the
// scheduler can hoist S vector loads / coeff s_loads several steps ahead
// (the unroll-2 window was the latency bottleneck at ~180 us). vfloat4
// accumulators: 64 VGPR acc + ~20 misc -> ~5 waves/SIMD.
// grid = (NDD/(256*CT)=64, NB/RB=128). Linear block id = x + 64*y, so
// XCD = id % 8 = x % 8: all blocks sharing a column stripe of S land on one
// XCD -> per-XCD unique S bytes ~1.2 MB, L2-resident. Nontemporal stores
// keep the 512 MB output stream from evicting S.
// ---------------------------------------------------------------------------
__global__ __launch_bounds__(256) void expand_kernel(
    const float* __restrict__ coeffT,   // [NK][NB]
    const float* __restrict__ S_poly,   // [NP][NDD]
    const float* __restrict__ S_graph,  // [NG][NDD]
    float* __restrict__ out)            // [NB][NDD]
{
    const int j  = (blockIdx.x * 256 + threadIdx.x) * CT;
    const int b0 = blockIdx.y * RB;

    const float* __restrict__ sp = S_poly  + j;
    const float* __restrict__ sg = S_graph + j;
    const float* __restrict__ cb = coeffT + b0;   // wave-uniform

    vfloat4 acc[RB];
    #pragma unroll
    for (int r = 0; r < RB; ++r) acc[r] = (vfloat4)0.f;

    vfloat4 sv = *(const vfloat4*)sp;   // k = 0
    #pragma unroll
    for (int k = 0; k < NK; ++k) {
        // prefetch next S row (compile-time select: k is a constant here)
        vfloat4 svn = sv;
        if (k + 1 < NK) {
            const float* nsrc = (k + 1 < NP)
                ? (sp + (size_t)(k + 1) * NDD)
                : (sg + (size_t)(k + 1 - NP) * NDD);
            svn = *(const vfloat4*)nsrc;
        }
        const float* cr = cb + (size_t)k * NB;    // uniform -> s_load
        vfloat4 c0 = *(const vfloat4*)(cr + 0);
        vfloat4 c1 = *(const vfloat4*)(cr + 4);
        vfloat4 c2 = *(const vfloat4*)(cr + 8);
        vfloat4 c3 = *(const vfloat4*)(cr + 12);
        #pragma unroll
        for (int r = 0; r < 4; ++r) acc[r     ] += c0[r] * sv;
        #pragma unroll
        for (int r = 0; r < 4; ++r) acc[r + 4 ] += c1[r] * sv;
        #pragma unroll
        for (int r = 0; r < 4; ++r) acc[r + 8 ] += c2[r] * sv;
        #pragma unroll
        for (int r = 0; r < 4; ++r) acc[r + 12] += c3[r] * sv;
        sv = svn;
    }

    #pragma unroll
    for (int r = 0; r < RB; ++r) {
        __builtin_nontemporal_store(
            acc[r], (vfloat4*)(out + (size_t)(b0 + r)*NDD + j));
    }
}

extern "C" void kernel_launch(void* const* d_in, const int* in_sizes, int n_in,
                              void* d_out, int out_size, void* d_ws, size_t ws_size,
                              hipStream_t stream) {
    const float* positions   = (const float*)d_in[0];
    const float* obs_pos     = (const float*)d_in[1];
    const float* poly_dic    = (const float*)d_in[2];
    const float* graph_dic   = (const float*)d_in[3];
    const float* alpha_poly  = (const float*)d_in[4];
    const float* alpha_graph = (const float*)d_in[5];
    const float* S_poly      = (const float*)d_in[6];
    const float* S_graph     = (const float*)d_in[7];
    float* out = (float*)d_out;

    float* coeffT = (float*)d_ws;   // NK*NB floats = 288 KB (transposed)

    knn_coeff_kernel<<<NB/QB, 256, 0, stream>>>(
        positions, obs_pos, poly_dic, graph_dic, alpha_poly, alpha_graph, coeffT);

    dim3 grid2(NDD/(256*CT), NB/RB);
    expand_kernel<<<grid2, 256, 0, stream>>>(coeffT, S_poly, S_graph, out);
}